// Round 11
// baseline (105.658 us; speedup 1.0000x reference)
//
#include <hip/hip_runtime.h>
#include <hip/hip_bf16.h>
#include <hip/hip_fp8.h>

constexpr int B_ = 4, T_ = 256, N_ = 200, D_ = 64, H_ = 4;
constexpr int BN_ = B_ * N_;
constexpr float LN_EPS = 1e-5f;
// fold 1/sqrt(dh)=0.25 and log2(e) into Q so p = exp2(score)
constexpr float QSCALE = 0.25f * 1.4426950408889634f;

typedef short short8_t __attribute__((ext_vector_type(8)));
typedef float f32x4 __attribute__((ext_vector_type(4)));

#if __has_builtin(__builtin_amdgcn_exp2f)
#define EXP2(x) __builtin_amdgcn_exp2f(x)
#else
#define EXP2(x) exp2f(x)
#endif

// ---- d_ws layout (bytes) ----
// Qg [800][4 h][256 q][16] fp8  (Q pre-scaled by QSCALE)
// Kg [800][4 h][256 s][16] fp8
// Vg [800][64 d][256 s]    fp8
// WoT [64 c][64 k] bf16 (written by block 0 of kernel A)
constexpr size_t WS_Q  = 0;
constexpr size_t WS_K  = 13107200;
constexpr size_t WS_V  = 26214400;
constexpr size_t WS_WO = 39321600;   // +8192 = 39329792 total (< 52.4MB ws)

__device__ __forceinline__ ushort f2bf(float f) {
    union { float f; unsigned u; } v; v.f = f;
    unsigned u = v.u + 0x7FFFu + ((v.u >> 16) & 1u);
    return (ushort)(u >> 16);
}

template <bool HI>
__device__ __forceinline__ unsigned cvt2fp8(float a, float b, unsigned old) {
#if __has_builtin(__builtin_amdgcn_cvt_pk_fp8_f32)
    return __builtin_amdgcn_cvt_pk_fp8_f32(a, b, old, HI);
#else
    __hip_fp8_e4m3 fa(a), fb(b);
    unsigned v = (unsigned)fa.__x | ((unsigned)fb.__x << 8);
    return HI ? ((old & 0x0000FFFFu) | (v << 16)) : ((old & 0xFFFF0000u) | v);
#endif
}

__device__ __forceinline__ f32x4 mfma_fp8(long long a, long long b, f32x4 c) {
    return __builtin_amdgcn_mfma_f32_16x16x32_fp8_fp8(a, b, c, 0, 0, 0);
}
__device__ __forceinline__ f32x4 mfma_bf16(short8_t a, short8_t b, f32x4 c) {
    return __builtin_amdgcn_mfma_f32_16x16x32_bf16(a, b, c, 0, 0, 0);
}

// ================= Kernel A: QKV projection -> fp8 ws (+ Wo -> bf16 ws) =========
// Proj-only register demand (~60). Short, X-read dominated.
__global__ __launch_bounds__(512, 4) void qkv_proj_kernel(
    const float* __restrict__ X,
    const float* __restrict__ Wq, const float* __restrict__ bq,
    const float* __restrict__ Wk, const float* __restrict__ bk,
    const float* __restrict__ Wv, const float* __restrict__ bv,
    const float* __restrict__ Wo,
    unsigned char* __restrict__ ws)
{
    __shared__ __align__(16) ushort sWT[64 * 72];

    const int bn   = blockIdx.x;
    const int b    = bn / N_;
    const int n    = bn - b * N_;
    const int tid  = threadIdx.x;
    const int lane = tid & 63;
    const int w    = tid >> 6;
    const int lm   = lane & 15;
    const int g    = lane >> 4;
    const int wbase = w * 32;

    const f32x4 zz = {0.f, 0.f, 0.f, 0.f};

    // X A/B-frags (rows wbase..wbase+31), bf16 in regs — same as r10
    short8_t af[2][2];
    #pragma unroll
    for (int mt = 0; mt < 2; ++mt) {
        #pragma unroll
        for (int kf = 0; kf < 2; ++kf) {
            const int t = wbase + mt * 16 + lm;
            const float* xp = X + (((long)(b * T_ + t)) * N_ + n) * D_ + kf * 32 + 8 * g;
            const float4 x0 = *(const float4*)xp;
            const float4 x1 = *(const float4*)(xp + 4);
            union { short8_t v; unsigned u[4]; } tmp;
            tmp.u[0] = ((unsigned)f2bf(x0.y) << 16) | f2bf(x0.x);
            tmp.u[1] = ((unsigned)f2bf(x0.w) << 16) | f2bf(x0.z);
            tmp.u[2] = ((unsigned)f2bf(x1.y) << 16) | f2bf(x1.x);
            tmp.u[3] = ((unsigned)f2bf(x1.w) << 16) | f2bf(x1.z);
            af[mt][kf] = tmp.v;
        }
    }

    const float* Wm[3] = {Wq, Wk, Wv};
    const float* bm[3] = {bq, bk, bv};
    #pragma unroll 1
    for (int m = 0; m < 3; ++m) {
        // stage W^T: pack two consecutive k per b32 write (r6-proven)
        for (int idx = tid; idx < 2048; idx += 512) {
            const int c = idx & 63, kp = idx >> 6;
            const unsigned lo = f2bf(Wm[m][(2 * kp) * 64 + c]);
            const unsigned hi = f2bf(Wm[m][(2 * kp + 1) * 64 + c]);
            *(unsigned*)&sWT[c * 72 + 2 * kp] = lo | (hi << 16);
        }
        __syncthreads();

        if (m < 2) {
            // swapped (lane holds 4 consecutive d at fixed q); dt == head (dh=16)
            unsigned char* dst = ws + ((m == 0) ? WS_Q : WS_K) + (size_t)bn * 16384;
            const float scl = (m == 0) ? QSCALE : 1.0f;
            #pragma unroll
            for (int dt = 0; dt < 4; ++dt) {
                const short8_t bf0 = *(const short8_t*)&sWT[(dt * 16 + lm) * 72 + 8 * g];
                const short8_t bf1 = *(const short8_t*)&sWT[(dt * 16 + lm) * 72 + 32 + 8 * g];
                const float4 bI = *(const float4*)(bm[m] + dt * 16 + 4 * g);
                #pragma unroll
                for (int q2 = 0; q2 < 2; ++q2) {
                    f32x4 acc = mfma_bf16(bf0, af[q2][0], zz);
                    acc = mfma_bf16(bf1, af[q2][1], acc);
                    unsigned pk = cvt2fp8<false>((acc[0] + bI.x) * scl, (acc[1] + bI.y) * scl, 0u);
                    pk = cvt2fp8<true>((acc[2] + bI.z) * scl, (acc[3] + bI.w) * scl, pk);
                    *(unsigned*)(dst + dt * 4096 + (wbase + q2 * 16 + lm) * 16 + 4 * g) = pk;
                }
            }
        } else {
            // V normal (lane holds 4 consecutive s at fixed d); row stride 256
            unsigned char* dst = ws + WS_V + (size_t)bn * 16384;
            #pragma unroll
            for (int nt = 0; nt < 4; ++nt) {
                const short8_t bf0 = *(const short8_t*)&sWT[(nt * 16 + lm) * 72 + 8 * g];
                const short8_t bf1 = *(const short8_t*)&sWT[(nt * 16 + lm) * 72 + 32 + 8 * g];
                const float blv = bm[2][nt * 16 + lm];
                #pragma unroll
                for (int mt = 0; mt < 2; ++mt) {
                    f32x4 acc = mfma_bf16(af[mt][0], bf0, zz);
                    acc = mfma_bf16(af[mt][1], bf1, acc);
                    unsigned pk = cvt2fp8<false>(acc[0] + blv, acc[1] + blv, 0u);
                    pk = cvt2fp8<true>(acc[2] + blv, acc[3] + blv, pk);
                    *(unsigned*)(dst + (nt * 16 + lm) * 256 + wbase + mt * 16 + 4 * g) = pk;
                }
            }
        }
        __syncthreads();   // protect sWT before next stage
    }

    // Wo -> bf16 ws (one block suffices; kernel boundary orders A before B)
    if (bn == 0) {
        ushort* wo = (ushort*)(ws + WS_WO);
        for (int idx = tid; idx < 2048; idx += 512) {
            const int c = idx & 63, kp = idx >> 6;
            const unsigned lo = f2bf(Wo[(2 * kp) * 64 + c]);
            const unsigned hi = f2bf(Wo[(2 * kp + 1) * 64 + c]);
            *(unsigned*)&wo[c * 64 + 2 * kp] = lo | (hi << 16);
        }
    }
}

// ================= Kernel B: attention + Wo + residual + LN =====================
// Attention-only register demand (~80) fits the (512,6) 85-reg budget -> 3
// blocks/CU; single barrier per block; Q/K/V read from ws (L3-resident).
__global__ __launch_bounds__(512, 6) void attn_out_kernel(
    const unsigned char* __restrict__ ws,
    const float* __restrict__ X,
    const float* __restrict__ bo,
    const float* __restrict__ gamma, const float* __restrict__ beta,
    float* __restrict__ out)
{
    __shared__ __align__(16) ushort sAttn[256 * 72];   // 36864 B

    const int bn   = blockIdx.x;
    const int b    = bn / N_;
    const int n    = bn - b * N_;
    const int tid  = threadIdx.x;
    const int lane = tid & 63;
    const int w    = tid >> 6;
    const int lm   = lane & 15;
    const int g    = lane >> 4;
    const int wbase = w * 32;

    const f32x4 zz = {0.f, 0.f, 0.f, 0.f};

    const unsigned char* Qg = ws + WS_Q + (size_t)bn * 16384;
    const unsigned char* Kg = ws + WS_K + (size_t)bn * 16384;
    const unsigned char* Vg = ws + WS_V + (size_t)bn * 16384;
    const ushort* WoT = (const ushort*)(ws + WS_WO);

    const int h     = w >> 1;
    const int qbase = (w & 1) * 128;
    const bool glo  = (g < 2);   // dh=16 < K=32: lane groups 2,3 carry zeros in QK

    #pragma unroll 1
    for (int pass = 0; pass < 2; ++pass) {
        const int qoff = qbase + pass * 64;
        long long qf[4];
        #pragma unroll
        for (int qt = 0; qt < 4; ++qt)
            qf[qt] = glo ? *(const long long*)(Qg + h * 4096 + (qoff + qt * 16 + lm) * 16 + 8 * g)
                         : 0ll;

        f32x4 oacc[4];
        float lsum[4];
        #pragma unroll
        for (int qt = 0; qt < 4; ++qt) { oacc[qt] = zz; lsum[qt] = 0.f; }

        #pragma unroll 1
        for (int c = 0; c < 8; ++c) {
            const long long kfe = glo ? *(const long long*)(Kg + h * 4096 + ((2 * c) * 16 + lm) * 16 + 8 * g) : 0ll;
            const long long kfo = glo ? *(const long long*)(Kg + h * 4096 + ((2 * c + 1) * 16 + lm) * 16 + 8 * g) : 0ll;
            const unsigned va = *(const unsigned*)(Vg + (h * 16 + lm) * 256 + 32 * c + 4 * g);
            const unsigned vb = *(const unsigned*)(Vg + (h * 16 + lm) * 256 + 32 * c + 16 + 4 * g);
            const long long vf = (long long)(((unsigned long long)vb << 32) | va);

            __builtin_amdgcn_s_setprio(1);
            #pragma unroll
            for (int qt = 0; qt < 4; ++qt) {
                const f32x4 se = mfma_fp8(kfe, qf[qt], zz);   // rows s=32c+4g+r, col q=lm
                const f32x4 so = mfma_fp8(kfo, qf[qt], zz);   // rows s=32c+16+4g+r
                const float pe0 = EXP2(se[0]), pe1 = EXP2(se[1]);
                const float pe2 = EXP2(se[2]), pe3 = EXP2(se[3]);
                const float po0 = EXP2(so[0]), po1 = EXP2(so[1]);
                const float po2 = EXP2(so[2]), po3 = EXP2(so[3]);
                lsum[qt] += ((pe0 + pe1) + (pe2 + pe3)) + ((po0 + po1) + (po2 + po3));
                unsigned a0 = cvt2fp8<false>(pe0, pe1, 0u); a0 = cvt2fp8<true>(pe2, pe3, a0);
                unsigned a1 = cvt2fp8<false>(po0, po1, 0u); a1 = cvt2fp8<true>(po2, po3, a1);
                const long long pa = (long long)(((unsigned long long)a1 << 32) | a0);
                oacc[qt] = mfma_fp8(pa, vf, oacc[qt]);
            }
            __builtin_amdgcn_s_setprio(0);
        }

        float inv[4];
        #pragma unroll
        for (int qt = 0; qt < 4; ++qt) {
            float t0 = lsum[qt] + __shfl_xor(lsum[qt], 16, 64);
            t0 += __shfl_xor(t0, 32, 64);
            inv[qt] = 1.0f / t0;
        }

        // sAttn is dedicated LDS: write immediately, no hazard
        #pragma unroll
        for (int qt = 0; qt < 4; ++qt)
            #pragma unroll
            for (int r = 0; r < 4; ++r) {
                const float iv = __shfl(inv[qt], 4 * g + r, 64);
                sAttn[(qoff + qt * 16 + 4 * g + r) * 72 + h * 16 + lm] = f2bf(oacc[qt][r] * iv);
            }
    }

    __syncthreads();   // the block's single barrier

    // ---------------- Wo projection + bias + residual + LayerNorm ----------------
    short8_t aF[2][2];
    #pragma unroll
    for (int mt = 0; mt < 2; ++mt)
        #pragma unroll
        for (int kf = 0; kf < 2; ++kf)
            aF[mt][kf] = *(const short8_t*)&sAttn[(wbase + mt * 16 + lm) * 72 + kf * 32 + 8 * g];

    f32x4 acc2[2][4];
    #pragma unroll
    for (int nt = 0; nt < 4; ++nt) {   // stream Wo frags from ws (8-reg transient)
        const short8_t wf0 = *(const short8_t*)&WoT[(nt * 16 + lm) * 64 + 8 * g];
        const short8_t wf1 = *(const short8_t*)&WoT[(nt * 16 + lm) * 64 + 32 + 8 * g];
        #pragma unroll
        for (int mt = 0; mt < 2; ++mt) {
            acc2[mt][nt] = mfma_bf16(aF[mt][0], wf0, zz);
            acc2[mt][nt] = mfma_bf16(aF[mt][1], wf1, acc2[mt][nt]);
        }
    }

    float bo_l[4], ga_l[4], be_l[4];
    #pragma unroll
    for (int nt = 0; nt < 4; ++nt) {
        bo_l[nt] = bo[nt * 16 + lm];
        ga_l[nt] = gamma[nt * 16 + lm];
        be_l[nt] = beta[nt * 16 + lm];
    }

    #pragma unroll
    for (int mt = 0; mt < 2; ++mt)
        #pragma unroll
        for (int r = 0; r < 4; ++r) {
            const int t = wbase + mt * 16 + 4 * g + r;
            const long base = (((long)(b * T_ + t)) * N_ + n) * D_;
            float v[4];
            #pragma unroll
            for (int nt = 0; nt < 4; ++nt)
                v[nt] = acc2[mt][nt][r] + bo_l[nt] + X[base + nt * 16 + lm];
            float s1 = (v[0] + v[1]) + (v[2] + v[3]);
            float s2 = (v[0] * v[0] + v[1] * v[1]) + (v[2] * v[2] + v[3] * v[3]);
            #pragma unroll
            for (int m = 1; m <= 8; m <<= 1) {
                s1 += __shfl_xor(s1, m, 64);
                s2 += __shfl_xor(s2, m, 64);
            }
            const float mu  = s1 * 0.015625f;
            const float var = s2 * 0.015625f - mu * mu;
            const float rs  = rsqrtf(var + LN_EPS);
            #pragma unroll
            for (int nt = 0; nt < 4; ++nt)
                out[base + nt * 16 + lm] = (v[nt] - mu) * rs * ga_l[nt] + be_l[nt];
        }
}

extern "C" void kernel_launch(void* const* d_in, const int* in_sizes, int n_in,
                              void* d_out, int out_size, void* d_ws, size_t ws_size,
                              hipStream_t stream) {
    const float* X     = (const float*)d_in[0];
    const float* Wq    = (const float*)d_in[1];
    const float* bq    = (const float*)d_in[2];
    const float* Wk    = (const float*)d_in[3];
    const float* bk    = (const float*)d_in[4];
    const float* Wv    = (const float*)d_in[5];
    const float* bv    = (const float*)d_in[6];
    const float* Wo    = (const float*)d_in[7];
    const float* bo    = (const float*)d_in[8];
    const float* gamma = (const float*)d_in[9];
    const float* beta  = (const float*)d_in[10];

    unsigned char* ws = (unsigned char*)d_ws;

    qkv_proj_kernel<<<BN_, 512, 0, stream>>>(X, Wq, bq, Wk, bk, Wv, bv, Wo, ws);
    attn_out_kernel<<<BN_, 512, 0, stream>>>(ws, X, bo, gamma, beta, (float*)d_out);
}

// Round 12
// 72.045 us; speedup vs baseline: 1.4665x; 1.4665x over previous
//
#include <hip/hip_runtime.h>
#include <hip/hip_bf16.h>
#include <hip/hip_fp8.h>

constexpr int B_ = 4, T_ = 256, N_ = 200, D_ = 64, H_ = 4;
constexpr int BN_ = B_ * N_;
constexpr float LN_EPS = 1e-5f;
// fold 1/sqrt(dh)=0.25 and log2(e) into Q so p = exp2(score)
constexpr float QSCALE = 0.25f * 1.4426950408889634f;

typedef short short8_t __attribute__((ext_vector_type(8)));
typedef float f32x4 __attribute__((ext_vector_type(4)));

#if __has_builtin(__builtin_amdgcn_exp2f)
#define EXP2(x) __builtin_amdgcn_exp2f(x)
#else
#define EXP2(x) exp2f(x)
#endif

#if __has_builtin(__builtin_amdgcn_rcpf)
#define RCP(x) __builtin_amdgcn_rcpf(x)
#else
#define RCP(x) (1.0f / (x))
#endif

// ---- arena byte offsets (r4/r10 layout: best measured) ----
// Qf8 [4 h][256 q][24]   fp8, 24576 B   (row stride 24, head stride 6144)
// Kf8 [4 h][256 s][24]   fp8, 24576 B
// Vf8 [64 d][272 s]      fp8, 17408 B
// sWT [64 c][72 k]       bf16, 9216 B
// sAttn bf16 [256][72] aliases bytes [0, 36864) (over Qf8+Kf8, dead by then)
constexpr int OFF_Q  = 0;
constexpr int OFF_K  = 24576;
constexpr int OFF_V  = 49152;
constexpr int OFF_WT = 66560;
constexpr int ARENA_BYTES = 75776;

__device__ __forceinline__ ushort f2bf(float f) {
    union { float f; unsigned u; } v; v.f = f;
    unsigned u = v.u + 0x7FFFu + ((v.u >> 16) & 1u);
    return (ushort)(u >> 16);
}

template <bool HI>
__device__ __forceinline__ unsigned cvt2fp8(float a, float b, unsigned old) {
#if __has_builtin(__builtin_amdgcn_cvt_pk_fp8_f32)
    return __builtin_amdgcn_cvt_pk_fp8_f32(a, b, old, HI);
#else
    __hip_fp8_e4m3 fa(a), fb(b);
    unsigned v = (unsigned)fa.__x | ((unsigned)fb.__x << 8);
    return HI ? ((old & 0x0000FFFFu) | (v << 16)) : ((old & 0xFFFF0000u) | v);
#endif
}

__device__ __forceinline__ f32x4 mfma_fp8(long long a, long long b, f32x4 c) {
    return __builtin_amdgcn_mfma_f32_16x16x32_fp8_fp8(a, b, c, 0, 0, 0);
}

// (512,4): r4-r11 evidence: per-wave demand ~124 unified regs; every attempt
// at 6 waves/EU (budget 85) spills (r5/r8/r11-B) at a net loss. Stay at 2
// blocks/CU, cut per-wave latency exposure instead (c-loop software pipeline).
__global__ __launch_bounds__(512, 4) void fused_attn_kernel(
    const float* __restrict__ X,
    const float* __restrict__ Wq, const float* __restrict__ bq,
    const float* __restrict__ Wk, const float* __restrict__ bk,
    const float* __restrict__ Wv, const float* __restrict__ bv,
    const float* __restrict__ Wo, const float* __restrict__ bo,
    const float* __restrict__ gamma, const float* __restrict__ beta,
    float* __restrict__ out)
{
    __shared__ __align__(16) unsigned char arena[ARENA_BYTES];
    unsigned char* Qf8 = arena + OFF_Q;
    unsigned char* Kf8 = arena + OFF_K;
    unsigned char* Vf8 = arena + OFF_V;
    ushort* sWT   = (ushort*)(arena + OFF_WT);
    ushort* sAttn = (ushort*)arena;          // [256][72] bf16 alias

    const int bn   = blockIdx.x;
    const int b    = bn / N_;
    const int n    = bn - b * N_;
    const int tid  = threadIdx.x;
    const int lane = tid & 63;
    const int w    = tid >> 6;        // wave 0..7
    const int lm   = lane & 15;
    const int g    = lane >> 4;       // 0..3
    const int wbase = w * 32;         // this wave's 32 X-rows for proj/epilogue

    const f32x4 zz = {0.f, 0.f, 0.f, 0.f};

    // ---------------- A/B-frags of X (rows wbase..wbase+31), bf16 in regs ----------
    short8_t af[2][2];
    #pragma unroll
    for (int mt = 0; mt < 2; ++mt) {
        #pragma unroll
        for (int kf = 0; kf < 2; ++kf) {
            const int t = wbase + mt * 16 + lm;
            const float* xp = X + (((long)(b * T_ + t)) * N_ + n) * D_ + kf * 32 + 8 * g;
            const float4 x0 = *(const float4*)xp;
            const float4 x1 = *(const float4*)(xp + 4);
            union { short8_t v; unsigned u[4]; } tmp;
            tmp.u[0] = ((unsigned)f2bf(x0.y) << 16) | f2bf(x0.x);
            tmp.u[1] = ((unsigned)f2bf(x0.w) << 16) | f2bf(x0.z);
            tmp.u[2] = ((unsigned)f2bf(x1.y) << 16) | f2bf(x1.x);
            tmp.u[3] = ((unsigned)f2bf(x1.w) << 16) | f2bf(x1.z);
            af[mt][kf] = tmp.v;
        }
    }

    // ---------------- QKV projections -> fp8 LDS ------------------------------------
    // Q,K computed swapped (lane holds 4 consecutive d at fixed q); V normal.
    const float* Wm[3] = {Wq, Wk, Wv};
    const float* bm[3] = {bq, bk, bv};
    #pragma unroll 1
    for (int m = 0; m < 3; ++m) {
        for (int idx = tid; idx < 4096; idx += 512) {
            const int k = idx >> 6, c = idx & 63;     // W[k][c], coalesced read
            sWT[c * 72 + k] = f2bf(Wm[m][idx]);
        }
        __syncthreads();

        short8_t bf[4][2];
        #pragma unroll
        for (int nt = 0; nt < 4; ++nt)
            #pragma unroll
            for (int kf = 0; kf < 2; ++kf)
                bf[nt][kf] = *(const short8_t*)&sWT[(nt * 16 + lm) * 72 + kf * 32 + 8 * g];

        __syncthreads();   // all frag reads done -> sWT slot reusable next m

        if (m < 2) {
            // swapped: accT[dt][q2] = (W^T X^T) tile; rows d = dt*16+4g+r, col q
            f32x4 accT[4][2];
            #pragma unroll
            for (int dt = 0; dt < 4; ++dt)
                #pragma unroll
                for (int q2 = 0; q2 < 2; ++q2) {
                    accT[dt][q2] = zz;
                    #pragma unroll
                    for (int kf = 0; kf < 2; ++kf)
                        accT[dt][q2] = __builtin_amdgcn_mfma_f32_16x16x32_bf16(
                            bf[dt][kf], af[q2][kf], accT[dt][q2], 0, 0, 0);
                }

            unsigned char* dst = (m == 0) ? Qf8 : Kf8;
            const float scl = (m == 0) ? QSCALE : 1.0f;
            #pragma unroll
            for (int dt = 0; dt < 4; ++dt) {
                const float4 bI = *(const float4*)(bm[m] + dt * 16 + 4 * g);
                #pragma unroll
                for (int q2 = 0; q2 < 2; ++q2) {
                    const float v0 = (accT[dt][q2][0] + bI.x) * scl;
                    const float v1 = (accT[dt][q2][1] + bI.y) * scl;
                    const float v2 = (accT[dt][q2][2] + bI.z) * scl;
                    const float v3 = (accT[dt][q2][3] + bI.w) * scl;
                    unsigned pk = cvt2fp8<false>(v0, v1, 0u);
                    pk = cvt2fp8<true>(v2, v3, pk);
                    const int q = wbase + q2 * 16 + lm;
                    *(unsigned*)(dst + dt * 6144 + q * 24 + 4 * g) = pk;
                }
            }
        } else {
            // normal: accV[mt][nt]; rows s = wbase+mt*16+4g+r, col d = nt*16+lm
            f32x4 accV[2][4];
            #pragma unroll
            for (int mt = 0; mt < 2; ++mt)
                #pragma unroll
                for (int nt = 0; nt < 4; ++nt) {
                    accV[mt][nt] = zz;
                    #pragma unroll
                    for (int kf = 0; kf < 2; ++kf)
                        accV[mt][nt] = __builtin_amdgcn_mfma_f32_16x16x32_bf16(
                            af[mt][kf], bf[nt][kf], accV[mt][nt], 0, 0, 0);
                }

            #pragma unroll
            for (int nt = 0; nt < 4; ++nt) {
                const float blv = bm[2][nt * 16 + lm];
                #pragma unroll
                for (int mt = 0; mt < 2; ++mt) {
                    const float v0 = accV[mt][nt][0] + blv;
                    const float v1 = accV[mt][nt][1] + blv;
                    const float v2 = accV[mt][nt][2] + blv;
                    const float v3 = accV[mt][nt][3] + blv;
                    unsigned pk = cvt2fp8<false>(v0, v1, 0u);
                    pk = cvt2fp8<true>(v2, v3, pk);
                    *(unsigned*)(Vf8 + (nt * 16 + lm) * 272 + wbase + mt * 16 + 4 * g) = pk;
                }
            }
        }
    }

    // stage Wo^T into the (now free) slot
    for (int idx = tid; idx < 4096; idx += 512) {
        const int k = idx >> 6, c = idx & 63;
        sWT[c * 72 + k] = f2bf(Wo[idx]);
    }
    __syncthreads();   // Qf8/Kf8/Vf8 + WoT visible

    // ---------------- attention: wave = (head h, query half), 2 passes of 4 qt ------
    const int h     = w >> 1;
    const int qbase = (w & 1) * 128;
    const bool glo  = (g < 2);   // dh=16 < K=32: lane groups 2,3 carry zeros in QK

    // fp8 e4m3 1.0 = 0x38 in every byte. lacc = P @ ones accumulates the softmax
    // denominator per row in the SAME lane/reg slot as oacc -> lane-local divide.
    const long long ONES8 = 0x3838383838383838ll;

    const unsigned char* Kbase = Kf8 + h * 6144 + lm * 24 + 8 * g;
    const unsigned char* Vbase = Vf8 + (h * 16 + lm) * 272 + 4 * g;

    f32x4 oacc[4], lacc[4];
    unsigned pend[8];   // pass-0 normalized bf16 rows (written after barrier)

    #pragma unroll 1
    for (int pass = 0; pass < 2; ++pass) {
        const int qoff = qbase + pass * 64;
        long long qf[4];
        #pragma unroll
        for (int qt = 0; qt < 4; ++qt)
            qf[qt] = glo ? *(const long long*)(Qf8 + h * 6144 + (qoff + qt * 16 + lm) * 24 + 8 * g)
                         : 0ll;
        #pragma unroll
        for (int qt = 0; qt < 4; ++qt) { oacc[qt] = zz; lacc[qt] = zz; }

        // -------- software-pipelined c-loop: prefetch tile c+1 during tile c --------
        long long kfeA = glo ? *(const long long*)(Kbase + 0 * 384) : 0ll;   // 16 rows * 24B
        long long kfoA = glo ? *(const long long*)(Kbase + 1 * 384) : 0ll;
        unsigned  vaA  = *(const unsigned*)(Vbase + 0);
        unsigned  vbA  = *(const unsigned*)(Vbase + 16);

        #pragma unroll 1
        for (int c = 0; c < 8; ++c) {
            long long kfeB = 0ll, kfoB = 0ll;
            unsigned  vaB = 0u, vbB = 0u;
            if (c < 7) {
                kfeB = glo ? *(const long long*)(Kbase + (2 * c + 2) * 384) : 0ll;
                kfoB = glo ? *(const long long*)(Kbase + (2 * c + 3) * 384) : 0ll;
                vaB  = *(const unsigned*)(Vbase + 32 * c + 32);
                vbB  = *(const unsigned*)(Vbase + 32 * c + 48);
            }
            const long long vf = (long long)(((unsigned long long)vbA << 32) | vaA);

            __builtin_amdgcn_s_setprio(1);   // T5: favor the MFMA/exp cluster
            #pragma unroll
            for (int qt = 0; qt < 4; ++qt) {
                const f32x4 se = mfma_fp8(kfeA, qf[qt], zz);   // rows s=32c+4g+r, col q=lm
                const f32x4 so = mfma_fp8(kfoA, qf[qt], zz);   // rows s=32c+16+4g+r
                const float pe0 = EXP2(se[0]), pe1 = EXP2(se[1]);
                const float pe2 = EXP2(se[2]), pe3 = EXP2(se[3]);
                const float po0 = EXP2(so[0]), po1 = EXP2(so[1]);
                const float po2 = EXP2(so[2]), po3 = EXP2(so[3]);
                unsigned a0 = cvt2fp8<false>(pe0, pe1, 0u); a0 = cvt2fp8<true>(pe2, pe3, a0);
                unsigned a1 = cvt2fp8<false>(po0, po1, 0u); a1 = cvt2fp8<true>(po2, po3, a1);
                const long long pa = (long long)(((unsigned long long)a1 << 32) | a0);
                oacc[qt] = mfma_fp8(pa, vf, oacc[qt]);
                lacc[qt] = mfma_fp8(pa, ONES8, lacc[qt]);
            }
            __builtin_amdgcn_s_setprio(0);

            kfeA = kfeB; kfoA = kfoB; vaA = vaB; vbA = vbB;
        }

        if (pass == 0) {
            #pragma unroll
            for (int qt = 0; qt < 4; ++qt) {
                pend[2 * qt] = ((unsigned)f2bf(oacc[qt][1] * RCP(lacc[qt][1])) << 16) |
                               f2bf(oacc[qt][0] * RCP(lacc[qt][0]));
                pend[2 * qt + 1] = ((unsigned)f2bf(oacc[qt][3] * RCP(lacc[qt][3])) << 16) |
                                   f2bf(oacc[qt][2] * RCP(lacc[qt][2]));
            }
        }
        // pass 1: oacc/lacc survive the loop
    }

    __syncthreads();   // all waves done reading Qf8/Kf8/Vf8 -> alias as sAttn

    // write pass-0 (pend) and pass-1 (oacc * rcp(lacc)) attention rows
    #pragma unroll
    for (int qt = 0; qt < 4; ++qt) {
        const int row0 = qbase + qt * 16 + 4 * g;
        sAttn[(row0 + 0) * 72 + h * 16 + lm] = (ushort)(pend[2 * qt] & 0xFFFFu);
        sAttn[(row0 + 1) * 72 + h * 16 + lm] = (ushort)(pend[2 * qt] >> 16);
        sAttn[(row0 + 2) * 72 + h * 16 + lm] = (ushort)(pend[2 * qt + 1] & 0xFFFFu);
        sAttn[(row0 + 3) * 72 + h * 16 + lm] = (ushort)(pend[2 * qt + 1] >> 16);
    }
    #pragma unroll
    for (int qt = 0; qt < 4; ++qt)
        #pragma unroll
        for (int r = 0; r < 4; ++r)
            sAttn[(qbase + 64 + qt * 16 + 4 * g + r) * 72 + h * 16 + lm] =
                f2bf(oacc[qt][r] * RCP(lacc[qt][r]));

    __syncthreads();

    // ---------------- Wo projection + bias + residual + LayerNorm -------------------
    short8_t wf[4][2];
    #pragma unroll
    for (int nt = 0; nt < 4; ++nt)
        #pragma unroll
        for (int kf = 0; kf < 2; ++kf)
            wf[nt][kf] = *(const short8_t*)&sWT[(nt * 16 + lm) * 72 + kf * 32 + 8 * g];

    short8_t aF[2][2];
    #pragma unroll
    for (int mt = 0; mt < 2; ++mt)
        #pragma unroll
        for (int kf = 0; kf < 2; ++kf)
            aF[mt][kf] = *(const short8_t*)&sAttn[(wbase + mt * 16 + lm) * 72 + kf * 32 + 8 * g];

    f32x4 acc2[2][4];
    #pragma unroll
    for (int mt = 0; mt < 2; ++mt)
        #pragma unroll
        for (int nt = 0; nt < 4; ++nt) {
            acc2[mt][nt] = zz;
            #pragma unroll
            for (int kf = 0; kf < 2; ++kf)
                acc2[mt][nt] = __builtin_amdgcn_mfma_f32_16x16x32_bf16(
                    aF[mt][kf], wf[nt][kf], acc2[mt][nt], 0, 0, 0);
        }

    float bo_l[4], ga_l[4], be_l[4];
    #pragma unroll
    for (int nt = 0; nt < 4; ++nt) {
        bo_l[nt] = bo[nt * 16 + lm];
        ga_l[nt] = gamma[nt * 16 + lm];
        be_l[nt] = beta[nt * 16 + lm];
    }

    #pragma unroll
    for (int mt = 0; mt < 2; ++mt)
        #pragma unroll
        for (int r = 0; r < 4; ++r) {
            const int t = wbase + mt * 16 + 4 * g + r;
            const long base = (((long)(b * T_ + t)) * N_ + n) * D_;
            float v[4];
            #pragma unroll
            for (int nt = 0; nt < 4; ++nt)
                v[nt] = acc2[mt][nt][r] + bo_l[nt] + X[base + nt * 16 + lm];
            float s1 = (v[0] + v[1]) + (v[2] + v[3]);
            float s2 = (v[0] * v[0] + v[1] * v[1]) + (v[2] * v[2] + v[3] * v[3]);
            #pragma unroll
            for (int m = 1; m <= 8; m <<= 1) {
                s1 += __shfl_xor(s1, m, 64);
                s2 += __shfl_xor(s2, m, 64);
            }
            const float mu  = s1 * 0.015625f;
            const float var = s2 * 0.015625f - mu * mu;
            const float rs  = rsqrtf(var + LN_EPS);
            #pragma unroll
            for (int nt = 0; nt < 4; ++nt)
                out[base + nt * 16 + lm] = (v[nt] - mu) * rs * ga_l[nt] + be_l[nt];
        }
}

extern "C" void kernel_launch(void* const* d_in, const int* in_sizes, int n_in,
                              void* d_out, int out_size, void* d_ws, size_t ws_size,
                              hipStream_t stream) {
    const float* X     = (const float*)d_in[0];
    const float* Wq    = (const float*)d_in[1];
    const float* bq    = (const float*)d_in[2];
    const float* Wk    = (const float*)d_in[3];
    const float* bk    = (const float*)d_in[4];
    const float* Wv    = (const float*)d_in[5];
    const float* bv    = (const float*)d_in[6];
    const float* Wo    = (const float*)d_in[7];
    const float* bo    = (const float*)d_in[8];
    const float* gamma = (const float*)d_in[9];
    const float* beta  = (const float*)d_in[10];

    fused_attn_kernel<<<BN_, 512, 0, stream>>>(
        X, Wq, bq, Wk, bk, Wv, bv, Wo, bo, gamma, beta, (float*)d_out);
}